// Round 9
// baseline (224.492 us; speedup 1.0000x reference)
//
#include <hip/hip_runtime.h>
#include <stdint.h>

#define BATCH 16
#define NPTS  20000
#define TOPK  1000
#define NKPT  20          // keys per thread (20*1024 >= 20000)
#define NBIN  2048
#define NCOPY 4
#define CANDCAP 1024

// LDS layout (byte offsets into one 163264-B buffer; phases overlay):
//   phase A (selection): klds 80000 | whist 32768 | cand 8192 | cand2 512
//   phase B/C (iou+sweep): suppT 131072 (overlays all of phase A)
//   persistent: boxes 16000 | areas 4000 | clsv 4000 | sel 8192
#define OFF_KLDS   0
#define OFF_WHIST  80000
#define OFF_CAND   112768
#define OFF_CAND2  120960
#define OFF_SUPPT  0
#define OFF_BOXES  131072
#define OFF_AREAS  147072
#define OFF_CLSV   151072
#define OFF_SEL    155072
#define SMEM_BYTES 163264

__device__ __forceinline__ uint32_t key_desc(float f) {
    // ascending transform, then invert -> sorting ascending by key gives cls descending
    uint32_t u = __float_as_uint(f);
    uint32_t m = (u & 0x80000000u) ? ~u : (u | 0x80000000u);
    return ~m;
}

__device__ __forceinline__ float key_undo(uint32_t k) {
    uint32_t m = ~k;
    uint32_t u = (m & 0x80000000u) ? (m & 0x7FFFFFFFu) : ~m;
    return __uint_as_float(u);
}

// Wave-aggregated list push (1 atomic per wave-op). Ballot covers active lanes only.
__device__ __forceinline__ void push64(bool pred, uint64_t val, int* cntr,
                                       uint64_t* list, int lane) {
    uint64_t mask = __ballot(pred);
    if (mask) {
        int first = __ffsll((long long)mask) - 1;
        int base = 0;
        if (lane == first) base = atomicAdd(cntr, (int)__popcll(mask));
        base = __shfl(base, first);
        if (pred) {
            int off = (int)__popcll(mask & ((1ull << lane) - 1ull));
            list[base + off] = val;
        }
    }
}

// Wave 0 picks the r-th smallest of lst[0..n) (n<=64, keys distinct).
__device__ __forceinline__ void wave_select(const uint64_t* lst, int n, int r,
                                            uint64_t* out, int wave, int lane) {
    if (wave == 0) {
        uint64_t my = (lane < n) ? lst[lane] : ~0ull;
        int rank = 0;
        for (int i = 0; i < n; ++i) { uint64_t o = __shfl(my, i); if (o < my) rank++; }
        if (lane < n && rank == r) *out = my;
    }
}

// Exact fallback for heavy ties: block-wide bit binary search over LDS keys.
__device__ uint64_t bit_search(const uint32_t* klds, uint64_t known, uint64_t kmask,
                               int startbit, uint32_t r, int* sh_c,
                               int tid, int lane) {
    for (int bit = startbit; bit >= 0; --bit) {
        if (tid == 0) *sh_c = 0;
        __syncthreads();
        uint32_t local = 0;
        #pragma unroll
        for (int j = 0; j < NKPT; ++j) {
            int p = tid + j * 1024;
            if (p < NPTS) {
                uint64_t k64 = ((uint64_t)klds[p] << 32) | (uint32_t)p;
                if ((k64 & kmask) == known && !((k64 >> bit) & 1ull)) local++;
            }
        }
        #pragma unroll
        for (int d = 1; d < 64; d <<= 1) local += __shfl_xor(local, d);
        if (lane == 0 && local) atomicAdd(sh_c, (int)local);
        __syncthreads();
        uint32_t c0 = (uint32_t)*sh_c;
        if (r >= c0) { known |= 1ull << bit; r -= c0; }
        kmask |= 1ull << bit;
        __syncthreads();
    }
    return known;
}

// Hierarchical scan over merged 2048-bin histogram; finds bin holding rank r.
__device__ __forceinline__ void hist_scan_find(
    uint32_t (*wh)[NBIN], uint32_t* wsum, uint32_t* wpre,
    int* sh_T, int* sh_r, int* sh_binc,
    int tid, int wave, int lane, uint32_t r)
{
    uint32_t m0 = 0, m1 = 0;
    #pragma unroll
    for (int cpy = 0; cpy < NCOPY; ++cpy) { m0 += wh[cpy][2*tid]; m1 += wh[cpy][2*tid+1]; }
    uint32_t s = m0 + m1, x = s;
    #pragma unroll
    for (int d = 1; d < 64; d <<= 1) { uint32_t t = __shfl_up(x, d); if (lane >= d) x += t; }
    if (lane == 63) wsum[wave] = x;
    __syncthreads();
    if (wave == 0 && lane < 16) {
        uint32_t v = wsum[lane], y = v;
        #pragma unroll
        for (int d = 1; d < 16; d <<= 1) { uint32_t t = __shfl_up(y, d); if (lane >= d) y += t; }
        wpre[lane] = y - v;
    }
    __syncthreads();
    uint32_t e = wpre[wave] + (x - s);
    if (r >= e && r < e + s) {
        if (r < e + m0) { *sh_T = 2*tid;     *sh_r = (int)(r - e);      *sh_binc = (int)m0; }
        else            { *sh_T = 2*tid + 1; *sh_r = (int)(r - e - m0); *sh_binc = (int)m1; }
    }
}

// ============ Single kernel: one block (1024 thr) does one batch ============
__global__ __launch_bounds__(1024, 4) void nms_batch(
    const float* __restrict__ reg, const float* __restrict__ cls,
    float* __restrict__ out)
{
    __shared__ __align__(16) uint8_t smem[SMEM_BYTES];
    __shared__ uint32_t wsum[16], wpre[16];
    __shared__ uint32_t skept[32];
    __shared__ int sh_T, sh_r, sh_binc, sh_cnt, sh_c;
    __shared__ uint64_t sh_kthkey;

    const int b = blockIdx.x, tid = threadIdx.x;
    const int wave = tid >> 6, lane = tid & 63;
    const float* c = cls + (size_t)b * NPTS;

    uint32_t* klds  = (uint32_t*)(smem + OFF_KLDS);
    uint32_t (*whist)[NBIN] = (uint32_t(*)[NBIN])(smem + OFF_WHIST);
    uint64_t* cand  = (uint64_t*)(smem + OFF_CAND);
    uint64_t* cand2 = (uint64_t*)(smem + OFF_CAND2);
    uint64_t* sel   = (uint64_t*)(smem + OFF_SEL);
    float4*   boxes = (float4*)(smem + OFF_BOXES);
    float*    areas = (float*)(smem + OFF_AREAS);
    float*    clsv  = (float*)(smem + OFF_CLSV);
    uint32_t* suppT = (uint32_t*)(smem + OFF_SUPPT);

    // ---- A1: zero hist; load keys -> LDS; 2048-bin histogram (top 11 bits)
    #pragma unroll
    for (int i = 0; i < NCOPY * NBIN / 1024; ++i) ((uint32_t*)whist)[tid + i * 1024] = 0;
    __syncthreads();
    #pragma unroll
    for (int j = 0; j < NKPT; ++j) {
        int p = tid + j * 1024;
        if (p < NPTS) {
            uint32_t k = key_desc(c[p]);
            klds[p] = k;
            atomicAdd(&whist[wave >> 2][k >> 21], 1u);
        }
    }
    __syncthreads();
    hist_scan_find(whist, wsum, wpre, &sh_T, &sh_r, &sh_binc, tid, wave, lane, TOPK - 1);
    __syncthreads();
    const uint32_t T1 = (uint32_t)sh_T;
    int r = sh_r;
    const int cnt1 = sh_binc;
    uint64_t known = (uint64_t)T1 << 53;

    // ---- A2: resolve exact kth key (two-level; exact fallbacks) ----
    if (cnt1 <= 64) {
        if (tid == 0) sh_cnt = 0;
        __syncthreads();
        #pragma unroll
        for (int j = 0; j < NKPT; ++j) {
            int p = tid + j * 1024;
            uint32_t k = (p < NPTS) ? klds[p] : 0xFFFFFFFFu;
            push64(p < NPTS && (k >> 21) == T1,
                   ((uint64_t)k << 32) | (uint32_t)p, &sh_cnt, cand2, lane);
        }
        __syncthreads();
        wave_select(cand2, cnt1, r, &sh_kthkey, wave, lane);
        __syncthreads();
    } else if (cnt1 <= CANDCAP) {
        if (tid == 0) sh_cnt = 0;
        __syncthreads();
        #pragma unroll
        for (int j = 0; j < NKPT; ++j) {
            int p = tid + j * 1024;
            uint32_t k = (p < NPTS) ? klds[p] : 0xFFFFFFFFu;
            push64(p < NPTS && (k >> 21) == T1,
                   ((uint64_t)k << 32) | (uint32_t)p, &sh_cnt, cand, lane);
        }
        __syncthreads();
        // second-level 2048-bin histogram over key bits 42..52 of candidates
        #pragma unroll
        for (int i = 0; i < NCOPY * NBIN / 1024; ++i) ((uint32_t*)whist)[tid + i * 1024] = 0;
        __syncthreads();
        for (int i = tid; i < cnt1; i += 1024)
            atomicAdd(&whist[wave >> 2][(uint32_t)((cand[i] >> 42) & 2047)], 1u);
        __syncthreads();
        hist_scan_find(whist, wsum, wpre, &sh_T, &sh_r, &sh_binc, tid, wave, lane, (uint32_t)r);
        __syncthreads();
        const uint32_t T2 = (uint32_t)sh_T; r = sh_r;
        const int cnt2 = sh_binc;
        known |= (uint64_t)T2 << 42;
        if (cnt2 <= 64) {
            if (tid == 0) sh_cnt = 0;
            __syncthreads();
            for (int i = tid; i < cnt1; i += 1024)
                push64(((cand[i] >> 42) & 2047) == (uint64_t)T2,
                       cand[i], &sh_cnt, cand2, lane);
            __syncthreads();
            wave_select(cand2, cnt2, r, &sh_kthkey, wave, lane);
            __syncthreads();
        } else {
            uint64_t kk = bit_search(klds, known, 0xFFFFFC0000000000ull, 41,
                                     (uint32_t)r, &sh_c, tid, lane);
            if (tid == 0) sh_kthkey = kk;
            __syncthreads();
        }
    } else {
        uint64_t kk = bit_search(klds, known, 0xFFE0000000000000ull, 52,
                                 (uint32_t)r, &sh_c, tid, lane);
        if (tid == 0) sh_kthkey = kk;
        __syncthreads();
    }
    const uint64_t kthkey = sh_kthkey;

    // ---- A3: gather exactly 1000 keys <= kthkey (wave-aggregated) ----
    if (tid == 0) sh_cnt = 0;
    sel[tid] = ~0ull;
    __syncthreads();
    #pragma unroll
    for (int j = 0; j < NKPT; ++j) {
        int p = tid + j * 1024;
        uint64_t key = (p < NPTS) ? (((uint64_t)klds[p] << 32) | (uint32_t)p) : ~0ull;
        push64(key <= kthkey, key, &sh_cnt, sel, lane);
    }
    __syncthreads();

    // ---- A4: all-pairs rank (keys distinct) -> sorted scatter into LDS ----
    {
        uint64_t e = sel[tid];
        int rk = 0;
        const ulonglong2* s2 = (const ulonglong2*)sel;
        #pragma unroll 8
        for (int m2 = 0; m2 < 512; ++m2) {
            ulonglong2 t2 = s2[m2];
            rk += (t2.x < e) ? 1 : 0;
            rk += (t2.y < e) ? 1 : 0;
        }
        if (e != ~0ull) {
            int p = (int)(e & 0xFFFFFFFFull);
            float4 v = ((const float4*)reg)[(size_t)b * NPTS + p];
            boxes[rk] = v;
            areas[rk] = (v.z - v.x) * (v.w - v.y);
            clsv[rk]  = key_undo((uint32_t)(e >> 32));
        }
    }
    __syncthreads();   // klds/whist/cand dead; suppT overlay may begin

    // ---- B: upper-triangle iou bitmask into LDS (transposed [word][row]) --
    // Lower-triangle words written as zeros (sweep provably never reads them).
    for (int i = wave; i < TOPK; i += 16) {
        float4 a = boxes[i];
        float areaA = areas[i];
        uint64_t mine = 0;
        for (int w2 = i >> 6; w2 < 16; ++w2) {
            int col = (w2 << 6) | lane;
            bool sup = false;
            if (col < TOPK) {
                float4 bb = boxes[col];
                float xx1 = fmaxf(a.x, bb.x);
                float yy1 = fmaxf(a.y, bb.y);
                float xx2 = fminf(a.z, bb.z);
                float yy2 = fminf(a.w, bb.w);
                float iw = fmaxf(xx2 - xx1, 0.0f);
                float ih = fmaxf(yy2 - yy1, 0.0f);
                float inter = iw * ih;
                float iou = inter / (areaA + areas[col] - inter);
                sup = (iou >= 0.5f);
            }
            uint64_t m = __ballot(sup);
            if (lane == w2) mine = m;
        }
        if (lane < 16) {
            suppT[(2 * lane + 0) * 1024 + i] = (uint32_t)(mine & 0xFFFFFFFFull);
            suppT[(2 * lane + 1) * 1024 + i] = (uint32_t)(mine >> 32);
        }
    }
    __syncthreads();

    // ---- C: group-32 greedy sweep (wave 0), LDS-resident bitmask ----------
    uint32_t keptw = 0;
    if (tid < 64) {
        const int myw = lane & 31;
        uint32_t remv = 0;
        #pragma unroll 1
        for (int W = 0; W < 32; ++W) {
            const uint4* dp = (const uint4*)(suppT + W * 1024 + W * 32);
            const uint4* cp = (const uint4*)(suppT + myw * 1024 + W * 32);
            uint4 dg[8], cl[8];
            #pragma unroll
            for (int k2 = 0; k2 < 8; ++k2) { dg[k2] = dp[k2]; cl[k2] = cp[k2]; }
            const int nb = (W == 31) ? (TOPK - 31 * 32) : 32;
            uint32_t cur = __shfl(remv, W);
            uint32_t kmask = 0, acc = 0;
#define STEP(D, C, BBIT) { \
    uint32_t live_ = (((~cur) >> (BBIT)) & 1u) & (uint32_t)((BBIT) < nb); \
    uint32_t msk_ = (uint32_t)0 - live_; \
    kmask |= (live_ << (BBIT)); \
    cur  |= (D) & msk_; \
    acc  |= (C) & msk_; }
            #pragma unroll
            for (int k2 = 0; k2 < 8; ++k2) {
                STEP(dg[k2].x, cl[k2].x, 4 * k2 + 0);
                STEP(dg[k2].y, cl[k2].y, 4 * k2 + 1);
                STEP(dg[k2].z, cl[k2].z, 4 * k2 + 2);
                STEP(dg[k2].w, cl[k2].w, 4 * k2 + 3);
            }
#undef STEP
            remv |= acc;
            if (myw == W) keptw = kmask;
        }
    }
    if (tid < 32) skept[tid] = keptw;
    __syncthreads();

    // ---- D: masked output write ----
    if (tid < TOPK) {
        uint32_t keep = (skept[tid >> 5] >> (tid & 31)) & 1u;
        float4 v = boxes[tid];
        float cv = clsv[tid];
        ((float4*)out)[(size_t)b * TOPK + tid] = keep ? v : make_float4(0.f, 0.f, 0.f, 0.f);
        out[(size_t)BATCH * TOPK * 4 + (size_t)b * TOPK + tid] = keep ? cv : 0.0f;
    }
}

extern "C" void kernel_launch(void* const* d_in, const int* in_sizes, int n_in,
                              void* d_out, int out_size, void* d_ws, size_t ws_size,
                              hipStream_t stream) {
    (void)in_sizes; (void)n_in; (void)out_size; (void)d_ws; (void)ws_size;
    const float* reg = (const float*)d_in[0];
    const float* cls = (const float*)d_in[1];
    float* out = (float*)d_out;

    nms_batch<<<dim3(BATCH), dim3(1024), 0, stream>>>(reg, cls, out);
}

// Round 10
// 84.967 us; speedup vs baseline: 2.6421x; 2.6421x over previous
//
#include <hip/hip_runtime.h>
#include <stdint.h>

#define BATCH 16
#define NPTS  20000
#define TOPK  1000
#define NKPT  20          // keys per thread (20*1024 >= 20000)
#define NBIN  2048
#define NCOPY 4
#define CANDCAP 1024

__device__ __forceinline__ uint32_t key_desc(float f) {
    // ascending transform, then invert -> sorting ascending by key gives cls descending
    uint32_t u = __float_as_uint(f);
    uint32_t m = (u & 0x80000000u) ? ~u : (u | 0x80000000u);
    return ~m;
}

__device__ __forceinline__ float key_undo(uint32_t k) {
    uint32_t m = ~k;
    uint32_t u = (m & 0x80000000u) ? (m & 0x7FFFFFFFu) : ~m;
    return __uint_as_float(u);
}

// Wave-aggregated list push (1 atomic per wave-op).
__device__ __forceinline__ void push64(bool pred, uint64_t val, int* cntr,
                                       uint64_t* list, int lane) {
    uint64_t mask = __ballot(pred);
    if (mask) {
        int first = __ffsll((long long)mask) - 1;
        int base = 0;
        if (lane == first) base = atomicAdd(cntr, (int)__popcll(mask));
        base = __shfl(base, first);
        if (pred) {
            int off = (int)__popcll(mask & ((1ull << lane) - 1ull));
            list[base + off] = val;
        }
    }
}

// Wave 0 picks the r-th smallest of lst[0..n) (n<=64, keys distinct).
__device__ __forceinline__ void wave_select(const uint64_t* lst, int n, int r,
                                            uint64_t* out, int wave, int lane) {
    if (wave == 0) {
        uint64_t my = (lane < n) ? lst[lane] : ~0ull;
        int rank = 0;
        for (int i = 0; i < n; ++i) { uint64_t o = __shfl(my, i); if (o < my) rank++; }
        if (lane < n && rank == r) *out = my;
    }
}

// Exact fallback for heavy ties: block-wide bit binary search over LDS keys.
__device__ uint64_t bit_search(const uint32_t* klds, uint64_t known, uint64_t kmask,
                               int startbit, uint32_t r, int* sh_c,
                               int tid, int lane) {
    for (int bit = startbit; bit >= 0; --bit) {
        if (tid == 0) *sh_c = 0;
        __syncthreads();
        uint32_t local = 0;
        #pragma unroll
        for (int j = 0; j < NKPT; ++j) {
            int p = tid + j * 1024;
            if (p < NPTS) {
                uint64_t k64 = ((uint64_t)klds[p] << 32) | (uint32_t)p;
                if ((k64 & kmask) == known && !((k64 >> bit) & 1ull)) local++;
            }
        }
        #pragma unroll
        for (int d = 1; d < 64; d <<= 1) local += __shfl_xor(local, d);
        if (lane == 0 && local) atomicAdd(sh_c, (int)local);
        __syncthreads();
        uint32_t c0 = (uint32_t)*sh_c;
        if (r >= c0) { known |= 1ull << bit; r -= c0; }
        kmask |= 1ull << bit;
        __syncthreads();
    }
    return known;
}

// Hierarchical scan over merged 2048-bin histogram; finds bin holding rank r.
__device__ __forceinline__ void hist_scan_find(
    uint32_t (*wh)[NBIN], uint32_t* wsum, uint32_t* wpre,
    int* sh_T, int* sh_r, int* sh_binc,
    int tid, int wave, int lane, uint32_t r)
{
    uint32_t m0 = 0, m1 = 0;
    #pragma unroll
    for (int cpy = 0; cpy < NCOPY; ++cpy) { m0 += wh[cpy][2*tid]; m1 += wh[cpy][2*tid+1]; }
    uint32_t s = m0 + m1, x = s;
    #pragma unroll
    for (int d = 1; d < 64; d <<= 1) { uint32_t t = __shfl_up(x, d); if (lane >= d) x += t; }
    if (lane == 63) wsum[wave] = x;
    __syncthreads();
    if (wave == 0 && lane < 16) {
        uint32_t v = wsum[lane], y = v;
        #pragma unroll
        for (int d = 1; d < 16; d <<= 1) { uint32_t t = __shfl_up(y, d); if (lane >= d) y += t; }
        wpre[lane] = y - v;
    }
    __syncthreads();
    uint32_t e = wpre[wave] + (x - s);
    if (r >= e && r < e + s) {
        if (r < e + m0) { *sh_T = 2*tid;     *sh_r = (int)(r - e);      *sh_binc = (int)m0; }
        else            { *sh_T = 2*tid + 1; *sh_r = (int)(r - e - m0); *sh_binc = (int)m1; }
    }
}

// ---------------- Kernel A: exact stable top-1000 per batch ----------------
// Selection: 2048-bin two-level threshold find (proven R5 path) + bucket-rank
// ordering (prefix over bins + within-bin rank; replaces bitonic/all-pairs).
__global__ __launch_bounds__(1024) void topk_kernel(
    const float* __restrict__ reg, const float* __restrict__ cls,
    float4* __restrict__ ws_boxes, float* __restrict__ ws_cls)
{
    __shared__ uint32_t klds[NPTS];        // 80000 B
    __shared__ uint32_t whist[NCOPY][NBIN];// 32768 B
    __shared__ uint32_t mpre[NBIN];        // 8192 B: exclusive prefix of merged bins
    __shared__ uint32_t bcnt[NBIN];        // 8192 B: per-bin scatter counters
    __shared__ uint64_t bucket[1024];      // 8192 B: bucketed selected keys
    __shared__ uint64_t cand[CANDCAP];     // 8192 B
    __shared__ uint64_t cand2[64];
    __shared__ uint32_t wsum[16], wpre16[16];
    __shared__ int      sh_T, sh_r, sh_binc, sh_cnt, sh_c;
    __shared__ uint64_t sh_kthkey;

    const int b = blockIdx.x, tid = threadIdx.x;
    const int wave = tid >> 6, lane = tid & 63;
    const float* c = cls + (size_t)b * NPTS;

    // ---- zero hist; load keys -> LDS; 2048-bin histogram (top 11 bits) ----
    #pragma unroll
    for (int i = 0; i < NCOPY * NBIN / 1024; ++i) ((uint32_t*)whist)[tid + i * 1024] = 0;
    __syncthreads();
    #pragma unroll
    for (int j = 0; j < NKPT; ++j) {
        int p = tid + j * 1024;
        if (p < NPTS) {
            uint32_t k = key_desc(c[p]);
            klds[p] = k;
            atomicAdd(&whist[wave >> 2][k >> 21], 1u);
        }
    }
    __syncthreads();

    // ---- merged scan: store full exclusive prefix + find rank-999 bin ----
    {
        uint32_t m0 = 0, m1 = 0;
        #pragma unroll
        for (int cpy = 0; cpy < NCOPY; ++cpy) { m0 += whist[cpy][2*tid]; m1 += whist[cpy][2*tid+1]; }
        uint32_t s = m0 + m1, x = s;
        #pragma unroll
        for (int d = 1; d < 64; d <<= 1) { uint32_t t = __shfl_up(x, d); if (lane >= d) x += t; }
        if (lane == 63) wsum[wave] = x;
        __syncthreads();
        if (wave == 0 && lane < 16) {
            uint32_t v = wsum[lane], y = v;
            #pragma unroll
            for (int d = 1; d < 16; d <<= 1) { uint32_t t = __shfl_up(y, d); if (lane >= d) y += t; }
            wpre16[lane] = y - v;
        }
        __syncthreads();
        uint32_t E = wpre16[wave] + (x - s);
        mpre[2*tid]   = E;
        mpre[2*tid+1] = E + m0;
        bcnt[2*tid] = 0; bcnt[2*tid+1] = 0;
        uint32_t r9 = TOPK - 1;
        if (r9 >= E && r9 < E + s) {
            if (r9 < E + m0) { sh_T = 2*tid;     sh_r = (int)(r9 - E);      sh_binc = (int)m0; }
            else             { sh_T = 2*tid + 1; sh_r = (int)(r9 - E - m0); sh_binc = (int)m1; }
        }
    }
    __syncthreads();
    const uint32_t T1 = (uint32_t)sh_T;
    int r = sh_r;
    const int cnt1 = sh_binc;
    uint64_t known = (uint64_t)T1 << 53;

    // ---- resolve exact kth key (two-level; exact fallbacks) ----
    if (cnt1 <= 64) {
        if (tid == 0) sh_cnt = 0;
        __syncthreads();
        #pragma unroll
        for (int j = 0; j < NKPT; ++j) {
            int p = tid + j * 1024;
            uint32_t k = (p < NPTS) ? klds[p] : 0xFFFFFFFFu;
            push64(p < NPTS && (k >> 21) == T1,
                   ((uint64_t)k << 32) | (uint32_t)p, &sh_cnt, cand2, lane);
        }
        __syncthreads();
        wave_select(cand2, cnt1, r, &sh_kthkey, wave, lane);
        __syncthreads();
    } else if (cnt1 <= CANDCAP) {
        if (tid == 0) sh_cnt = 0;
        __syncthreads();
        #pragma unroll
        for (int j = 0; j < NKPT; ++j) {
            int p = tid + j * 1024;
            uint32_t k = (p < NPTS) ? klds[p] : 0xFFFFFFFFu;
            push64(p < NPTS && (k >> 21) == T1,
                   ((uint64_t)k << 32) | (uint32_t)p, &sh_cnt, cand, lane);
        }
        __syncthreads();
        // second-level 2048-bin histogram over key bits 42..52 of candidates
        #pragma unroll
        for (int i = 0; i < NCOPY * NBIN / 1024; ++i) ((uint32_t*)whist)[tid + i * 1024] = 0;
        __syncthreads();
        for (int i = tid; i < cnt1; i += 1024)
            atomicAdd(&whist[wave >> 2][(uint32_t)((cand[i] >> 42) & 2047)], 1u);
        __syncthreads();
        hist_scan_find(whist, wsum, wpre16, &sh_T, &sh_r, &sh_binc, tid, wave, lane, (uint32_t)r);
        __syncthreads();
        const uint32_t T2 = (uint32_t)sh_T; r = sh_r;
        const int cnt2 = sh_binc;
        known |= (uint64_t)T2 << 42;
        if (cnt2 <= 64) {
            if (tid == 0) sh_cnt = 0;
            __syncthreads();
            for (int i = tid; i < cnt1; i += 1024)
                push64(((cand[i] >> 42) & 2047) == (uint64_t)T2,
                       cand[i], &sh_cnt, cand2, lane);
            __syncthreads();
            wave_select(cand2, cnt2, r, &sh_kthkey, wave, lane);
            __syncthreads();
        } else {
            uint64_t kk = bit_search(klds, known, 0xFFFFFC0000000000ull, 41,
                                     (uint32_t)r, &sh_c, tid, lane);
            if (tid == 0) sh_kthkey = kk;
            __syncthreads();
        }
    } else {
        uint64_t kk = bit_search(klds, known, 0xFFE0000000000000ull, 52,
                                 (uint32_t)r, &sh_c, tid, lane);
        if (tid == 0) sh_kthkey = kk;
        __syncthreads();
    }
    const uint64_t kthkey = sh_kthkey;

    // ---- bucket-scatter: selected keys into their bin segments ----
    // For bins t <= T1 all-keys prefix == selected prefix, so positions are
    // exactly [0, 1000). Within-bin order is arbitrary here.
    #pragma unroll
    for (int j = 0; j < NKPT; ++j) {
        int p = tid + j * 1024;
        if (p < NPTS) {
            uint32_t k = klds[p];
            uint64_t key = ((uint64_t)k << 32) | (uint32_t)p;
            if (key <= kthkey) {
                uint32_t t = k >> 21;
                uint32_t pos = mpre[t] + atomicAdd(&bcnt[t], 1u);
                bucket[pos] = key;
            }
        }
    }
    __syncthreads();

    // ---- within-bin rank (segment <= ~240) -> direct sorted scatter ----
    if (tid < TOPK) {
        uint64_t e = bucket[tid];
        uint32_t t = (uint32_t)(e >> 53);
        uint32_t base = mpre[t], n = bcnt[t];
        int rank = (int)base;
        for (uint32_t q = 0; q < n; ++q) rank += (bucket[base + q] < e) ? 1 : 0;
        int p = (int)(e & 0xFFFFFFFFull);
        ws_boxes[b * TOPK + rank] = ((const float4*)reg)[(size_t)b * NPTS + p];
        ws_cls[b * TOPK + rank] = key_undo((uint32_t)(e >> 32));
    }
}

// ---------------- Kernel B: upper-triangle iou bitmask, TRANSPOSED ----------
// suppT[b][word w][row i] = bits: columns 32w..32w+31 of supp row i.
// Lower-triangle words written as zeros (sweep provably never uses them).
// Rows interleaved across blocks (block j: rows j, j+16, ...) to balance the
// triangle: ~8.5 col-group units/block instead of 16.
__global__ __launch_bounds__(256) void iou_kernel(
    const float4* __restrict__ ws_boxes, uint32_t* __restrict__ suppT)
{
    __shared__ float4 boxes[TOPK];
    __shared__ float  areas[TOPK];
    const int b   = blockIdx.y;
    const int j   = blockIdx.x;       // 0..15 row residue
    const int tid = threadIdx.x;
    for (int i = tid; i < TOPK; i += 256) {
        float4 v = ws_boxes[b * TOPK + i];
        boxes[i] = v;
        areas[i] = (v.z - v.x) * (v.w - v.y);
    }
    __syncthreads();

    const int lane = tid & 63;
    const int wave = tid >> 6;        // 0..3
    uint32_t* t = suppT + (size_t)b * 32 * 1024;

    for (int k = wave; ; k += 4) {
        const int i = j + (k << 4);
        if (i >= TOPK) break;
        float4 a = boxes[i];
        float areaA = areas[i];
        uint64_t mine = 0;
        for (int w2 = i >> 6; w2 < 16; ++w2) {   // upper triangle only
            int col = (w2 << 6) | lane;
            bool sup = false;
            if (col < TOPK) {
                float4 bb = boxes[col];
                float xx1 = fmaxf(a.x, bb.x);
                float yy1 = fmaxf(a.y, bb.y);
                float xx2 = fminf(a.z, bb.z);
                float yy2 = fminf(a.w, bb.w);
                float iw = fmaxf(xx2 - xx1, 0.0f);
                float ih = fmaxf(yy2 - yy1, 0.0f);
                float inter = iw * ih;
                float iou = inter / (areaA + areas[col] - inter);
                sup = (iou >= 0.5f);
            }
            uint64_t m = __ballot(sup);
            if (lane == w2) mine = m;
        }
        if (lane < 16) {
            t[(2 * lane + 0) * 1024 + i] = (uint32_t)(mine & 0xFFFFFFFFull);
            t[(2 * lane + 1) * 1024 + i] = (uint32_t)(mine >> 32);
        }
    }
}

// ---------------- Kernel C: group-32 greedy sweep + output ----------------
__global__ __launch_bounds__(64) void sweep_kernel(
    const uint32_t* __restrict__ suppT, const float4* __restrict__ ws_boxes,
    const float* __restrict__ ws_cls, float* __restrict__ out)
{
    const int b    = blockIdx.x;
    const int lane = threadIdx.x;
    const int myw  = lane & 31;
    const uint32_t* base = suppT + (size_t)b * 32 * 1024;

    uint32_t remv = 0, keptw = 0;
    uint4 dgA[8], clA[8], dgB[8], clB[8];

#define LOADG(W, DG, CL) { \
    const uint4* dp_ = (const uint4*)(base + (W) * 1024 + (W) * 32); \
    const uint4* cp_ = (const uint4*)(base + myw * 1024 + (W) * 32); \
    _Pragma("unroll") \
    for (int k_ = 0; k_ < 8; ++k_) { DG[k_] = dp_[k_]; CL[k_] = cp_[k_]; } }

#define STEP(D, C, BBIT) { \
    uint32_t live_ = (((~cur) >> (BBIT)) & 1u) & (uint32_t)((BBIT) < nb); \
    uint32_t msk_ = (uint32_t)0 - live_; \
    kmask |= (live_ << (BBIT)); \
    cur  |= (D) & msk_; \
    acc  |= (C) & msk_; }

#define PROC(W, DG, CL) { \
    const int nb = ((W) == 31) ? (TOPK - 31 * 32) : 32; \
    uint32_t cur = __shfl(remv, (W)); \
    uint32_t kmask = 0, acc = 0; \
    _Pragma("unroll") \
    for (int k_ = 0; k_ < 8; ++k_) { \
        STEP(DG[k_].x, CL[k_].x, 4 * k_ + 0); \
        STEP(DG[k_].y, CL[k_].y, 4 * k_ + 1); \
        STEP(DG[k_].z, CL[k_].z, 4 * k_ + 2); \
        STEP(DG[k_].w, CL[k_].w, 4 * k_ + 3); \
    } \
    remv |= acc; \
    if (myw == (W)) keptw = kmask; }

    LOADG(0, dgA, clA);
    #pragma unroll 1
    for (int w2 = 0; w2 < 16; ++w2) {
        const int wE = 2 * w2, wO = 2 * w2 + 1;
        LOADG(wO, dgB, clB);          // prefetch odd group
        PROC(wE, dgA, clA);
        if (wO + 1 < 32) LOADG(wO + 1, dgA, clA);   // prefetch next even group
        PROC(wO, dgB, clB);
    }

    __shared__ uint32_t skept[32];
    if (lane < 32) skept[lane] = keptw;
    __syncthreads();

    const float4* bx = ws_boxes + (size_t)b * TOPK;
    const float*  bc = ws_cls + (size_t)b * TOPK;
    float4* outr = (float4*)out + (size_t)b * TOPK;
    float*  outc = out + (size_t)BATCH * TOPK * 4 + (size_t)b * TOPK;
    for (int i = lane; i < TOPK; i += 64) {
        uint32_t keep = (skept[i >> 5] >> (i & 31)) & 1u;
        float4 v = bx[i];
        float cv = bc[i];
        outr[i] = keep ? v : make_float4(0.f, 0.f, 0.f, 0.f);
        outc[i] = keep ? cv : 0.0f;
    }
#undef LOADG
#undef STEP
#undef PROC
}

extern "C" void kernel_launch(void* const* d_in, const int* in_sizes, int n_in,
                              void* d_out, int out_size, void* d_ws, size_t ws_size,
                              hipStream_t stream) {
    (void)in_sizes; (void)n_in; (void)out_size; (void)ws_size;
    const float* reg = (const float*)d_in[0];
    const float* cls = (const float*)d_in[1];
    float* out = (float*)d_out;
    char* ws = (char*)d_ws;

    float4*   ws_boxes = (float4*)ws;                      // 16*1000*16 = 256000 B
    float*    ws_cls   = (float*)(ws + 256000);            // 64000 B
    uint32_t* suppT    = (uint32_t*)(ws + 320000);         // 16*32*1024*4 = 2097152 B

    topk_kernel<<<dim3(BATCH), dim3(1024), 0, stream>>>(reg, cls, ws_boxes, ws_cls);
    iou_kernel<<<dim3(16, BATCH), dim3(256), 0, stream>>>(ws_boxes, suppT);
    sweep_kernel<<<dim3(BATCH), dim3(64), 0, stream>>>(suppT, ws_boxes, ws_cls, out);
}

// Round 11
// 83.346 us; speedup vs baseline: 2.6935x; 1.0195x over previous
//
#include <hip/hip_runtime.h>
#include <stdint.h>

#define BATCH 16
#define NPTS  20000
#define TOPK  1000
#define NKPT  20          // keys per thread (20*1024 >= 20000)
#define NBIN  2048
#define NCOPY 4
#define CANDCAP 2048

__device__ __forceinline__ uint32_t key_desc(float f) {
    // ascending transform, then invert -> sorting ascending by k gives cls descending
    uint32_t u = __float_as_uint(f);
    uint32_t m = (u & 0x80000000u) ? ~u : (u | 0x80000000u);
    return ~m;
}

__device__ __forceinline__ float key_undo(uint32_t k) {
    uint32_t m = ~k;
    uint32_t u = (m & 0x80000000u) ? (m & 0x7FFFFFFFu) : ~m;
    return __uint_as_float(u);
}

// Wave-aggregated list push (1 atomic per wave-op).
__device__ __forceinline__ void push64(bool pred, uint64_t val, int* cntr,
                                       uint64_t* list, int lane) {
    uint64_t mask = __ballot(pred);
    if (mask) {
        int first = __ffsll((long long)mask) - 1;
        int base = 0;
        if (lane == first) base = atomicAdd(cntr, (int)__popcll(mask));
        base = __shfl(base, first);
        if (pred) {
            int off = (int)__popcll(mask & ((1ull << lane) - 1ull));
            list[base + off] = val;
        }
    }
}

// Wave 0 picks the r-th smallest of lst[0..n) (n<=64, keys distinct).
__device__ __forceinline__ void wave_select(const uint64_t* lst, int n, int r,
                                            uint64_t* out, int wave, int lane) {
    if (wave == 0) {
        uint64_t my = (lane < n) ? lst[lane] : ~0ull;
        int rank = 0;
        for (int i = 0; i < n; ++i) { uint64_t o = __shfl(my, i); if (o < my) rank++; }
        if (lane < n && rank == r) *out = my;
    }
}

// Exact fallback for heavy ties: block-wide bit binary search over register keys.
__device__ uint64_t bit_search(const uint32_t* kreg, uint64_t known, uint64_t kmask,
                               int startbit, uint32_t r, int* sh_c,
                               int tid, int lane) {
    for (int bit = startbit; bit >= 0; --bit) {
        if (tid == 0) *sh_c = 0;
        __syncthreads();
        uint32_t local = 0;
        #pragma unroll
        for (int j = 0; j < NKPT; ++j) {
            int p = tid + j * 1024;
            uint64_t k64 = ((uint64_t)kreg[j] << 32) | (uint32_t)p;
            if (p < NPTS && (k64 & kmask) == known && !((k64 >> bit) & 1ull)) local++;
        }
        #pragma unroll
        for (int d = 1; d < 64; d <<= 1) local += __shfl_xor(local, d);
        if (lane == 0 && local) atomicAdd(sh_c, (int)local);
        __syncthreads();
        uint32_t c0 = (uint32_t)*sh_c;
        if (r >= c0) { known |= 1ull << bit; r -= c0; }
        kmask |= 1ull << bit;
        __syncthreads();
    }
    return known;
}

// Hierarchical scan over merged 2048-bin histogram; finds bin holding rank r.
__device__ __forceinline__ void hist_scan_find(
    uint32_t (*wh)[NBIN], uint32_t* wsum, uint32_t* wpre,
    int* sh_T, int* sh_r, int* sh_binc,
    int tid, int wave, int lane, uint32_t r)
{
    uint32_t m0 = 0, m1 = 0;
    #pragma unroll
    for (int cpy = 0; cpy < NCOPY; ++cpy) { m0 += wh[cpy][2*tid]; m1 += wh[cpy][2*tid+1]; }
    uint32_t s = m0 + m1, x = s;
    #pragma unroll
    for (int d = 1; d < 64; d <<= 1) { uint32_t t = __shfl_up(x, d); if (lane >= d) x += t; }
    if (lane == 63) wsum[wave] = x;
    __syncthreads();
    if (wave == 0 && lane < 16) {
        uint32_t v = wsum[lane], y = v;
        #pragma unroll
        for (int d = 1; d < 16; d <<= 1) { uint32_t t = __shfl_up(y, d); if (lane >= d) y += t; }
        wpre[lane] = y - v;
    }
    __syncthreads();
    uint32_t e = wpre[wave] + (x - s);
    if (r >= e && r < e + s) {
        if (r < e + m0) { *sh_T = 2*tid;     *sh_r = (int)(r - e);      *sh_binc = (int)m0; }
        else            { *sh_T = 2*tid + 1; *sh_r = (int)(r - e - m0); *sh_binc = (int)m1; }
    }
}

// ---------------- Kernel A: exact stable top-1000 per batch ----------------
// R4-proven selection (kreg + two-level 2048-bin + push64 gather) with the
// bitonic sort replaced by barrier-free wave-sort + rank-merge scatter.
__global__ __launch_bounds__(1024, 4) void topk_kernel(
    const float* __restrict__ reg, const float* __restrict__ cls,
    float4* __restrict__ ws_boxes, float* __restrict__ ws_cls)
{
    __shared__ uint32_t whist[NCOPY][NBIN];   // 32768 B
    __shared__ uint32_t wsum[16], wpre[16];
    __shared__ int      sh_T, sh_r, sh_binc, sh_cnt, sh_c;
    __shared__ uint64_t sh_kthkey;
    __shared__ uint64_t cand[CANDCAP];        // 16384 B
    __shared__ uint64_t cand2[64];
    __shared__ uint64_t sel[1024];            // 8192 B

    const int b = blockIdx.x, tid = threadIdx.x;
    const int wave = tid >> 6, lane = tid & 63;
    const float* c = cls + (size_t)b * NPTS;

    if (tid == 0) { sh_cnt = 0; }

    // ---- cache all keys in registers (20 per thread) + zero hist ----
    #pragma unroll
    for (int i = 0; i < NCOPY * NBIN / 1024; ++i) ((uint32_t*)whist)[tid + i * 1024] = 0;
    uint32_t kreg[NKPT];
    #pragma unroll
    for (int j = 0; j < NKPT; ++j) {
        int p = tid + j * 1024;
        kreg[j] = (p < NPTS) ? key_desc(c[p]) : 0xFFFFFFFFu;
    }
    __syncthreads();

    // ---- 2048-bin histogram over top 11 key bits ----
    #pragma unroll
    for (int j = 0; j < NKPT; ++j) {
        int p = tid + j * 1024;
        if (p < NPTS) atomicAdd(&whist[wave >> 2][kreg[j] >> 21], 1u);
    }
    __syncthreads();
    hist_scan_find(whist, wsum, wpre, &sh_T, &sh_r, &sh_binc, tid, wave, lane, TOPK - 1);
    __syncthreads();
    const uint32_t T1 = (uint32_t)sh_T;
    int r = sh_r;
    const int cnt1 = sh_binc;
    uint64_t known = (uint64_t)T1 << 53;

    // ---- resolve exact kth key (two-level; exact fallbacks) ----
    if (cnt1 <= 64) {
        __syncthreads();
        #pragma unroll
        for (int j = 0; j < NKPT; ++j) {
            int p = tid + j * 1024;
            push64(p < NPTS && (kreg[j] >> 21) == T1,
                   ((uint64_t)kreg[j] << 32) | (uint32_t)p, &sh_cnt, cand2, lane);
        }
        __syncthreads();
        wave_select(cand2, cnt1, r, &sh_kthkey, wave, lane);
        __syncthreads();
    } else if (cnt1 <= CANDCAP) {
        __syncthreads();
        #pragma unroll
        for (int j = 0; j < NKPT; ++j) {
            int p = tid + j * 1024;
            push64(p < NPTS && (kreg[j] >> 21) == T1,
                   ((uint64_t)kreg[j] << 32) | (uint32_t)p, &sh_cnt, cand, lane);
        }
        __syncthreads();
        // second-level 2048-bin histogram over key bits 42..52 of candidates
        #pragma unroll
        for (int i = 0; i < NCOPY * NBIN / 1024; ++i) ((uint32_t*)whist)[tid + i * 1024] = 0;
        __syncthreads();
        for (int i = tid; i < cnt1; i += 1024)
            atomicAdd(&whist[wave >> 2][(uint32_t)((cand[i] >> 42) & 2047)], 1u);
        __syncthreads();
        hist_scan_find(whist, wsum, wpre, &sh_T, &sh_r, &sh_binc, tid, wave, lane, (uint32_t)r);
        __syncthreads();
        const uint32_t T2 = (uint32_t)sh_T; r = sh_r;
        const int cnt2 = sh_binc;
        known |= (uint64_t)T2 << 42;
        if (cnt2 <= 64) {
            if (tid == 0) sh_cnt = 0;
            __syncthreads();
            for (int i = tid; i < cnt1; i += 1024)
                push64(((cand[i] >> 42) & 2047) == (uint64_t)T2,
                       cand[i], &sh_cnt, cand2, lane);
            __syncthreads();
            wave_select(cand2, cnt2, r, &sh_kthkey, wave, lane);
            __syncthreads();
        } else {
            uint64_t kk = bit_search(kreg, known, 0xFFFFFC0000000000ull, 41,
                                     (uint32_t)r, &sh_c, tid, lane);
            if (tid == 0) sh_kthkey = kk;
            __syncthreads();
        }
    } else {
        uint64_t kk = bit_search(kreg, known, 0xFFE0000000000000ull, 52,
                                 (uint32_t)r, &sh_c, tid, lane);
        if (tid == 0) sh_kthkey = kk;
        __syncthreads();
    }
    const uint64_t kthkey = sh_kthkey;

    // ---- gather exactly 1000 keys <= kthkey (wave-aggregated) ----
    if (tid == 0) sh_cnt = 0;
    sel[tid] = ~0ull;
    __syncthreads();
    #pragma unroll
    for (int j = 0; j < NKPT; ++j) {
        int p = tid + j * 1024;
        uint64_t key = ((uint64_t)kreg[j] << 32) | (uint32_t)p;
        push64(p < NPTS && key <= kthkey, key, &sh_cnt, sel, lane);
    }
    __syncthreads();

    // ---- wave-sort (in-register, barrier-free) + rank-merge scatter ----
    uint64_t e = sel[tid];
    #pragma unroll
    for (int k = 2; k <= 64; k <<= 1) {
        #pragma unroll
        for (int j = k >> 1; j >= 1; j >>= 1) {
            uint64_t o = __shfl_xor(e, j);
            uint64_t lo = (e < o) ? e : o;
            uint64_t hi = (e < o) ? o : e;
            bool dir   = (lane & k) == 0;     // ascending sub-sequence
            bool upper = (lane & j) != 0;
            e = (upper == dir) ? hi : lo;
        }
    }
    sel[tid] = e;                             // wave's sorted 64-run (own slots)
    __syncthreads();
    int grank = lane;                         // rank within own wave (distinct keys)
    #pragma unroll 1
    for (int w2 = 0; w2 < 16; ++w2) {
        if (w2 == wave) continue;
        const uint64_t* bp = &sel[w2 * 64];
        int cf = 0;
        #pragma unroll
        for (int s = 32; s >= 1; s >>= 1) {
            int t2 = cf + s;
            if (bp[t2 - 1] < e) cf = t2;
        }
        if (bp[cf] < e) cf++;                 // count may reach 64
        grank += cf;
    }
    if (e != ~0ull) {
        int p = (int)(e & 0xFFFFFFFFull);
        ws_boxes[b * TOPK + grank] = ((const float4*)reg)[(size_t)b * NPTS + p];
        ws_cls[b * TOPK + grank] = key_undo((uint32_t)(e >> 32));
    }
}

// ---------------- Kernel B: upper-triangle iou bitmask, TRANSPOSED ----------
// suppT[b][word w][row i] = bits: columns 32w..32w+31 of supp row i.
// Lower-triangle words written as zeros (sweep provably never uses them).
// Rows interleaved across blocks (block j: rows j, j+16, ...) for balance.
__global__ __launch_bounds__(256) void iou_kernel(
    const float4* __restrict__ ws_boxes, uint32_t* __restrict__ suppT)
{
    __shared__ float4 boxes[TOPK];
    __shared__ float  areas[TOPK];
    const int b   = blockIdx.y;
    const int j   = blockIdx.x;       // 0..15 row residue
    const int tid = threadIdx.x;
    for (int i = tid; i < TOPK; i += 256) {
        float4 v = ws_boxes[b * TOPK + i];
        boxes[i] = v;
        areas[i] = (v.z - v.x) * (v.w - v.y);
    }
    __syncthreads();

    const int lane = tid & 63;
    const int wave = tid >> 6;        // 0..3
    uint32_t* t = suppT + (size_t)b * 32 * 1024;

    for (int k = wave; ; k += 4) {
        const int i = j + (k << 4);
        if (i >= TOPK) break;
        float4 a = boxes[i];
        float areaA = areas[i];
        uint64_t mine = 0;
        for (int w2 = i >> 6; w2 < 16; ++w2) {   // upper triangle only
            int col = (w2 << 6) | lane;
            bool sup = false;
            if (col < TOPK) {
                float4 bb = boxes[col];
                float xx1 = fmaxf(a.x, bb.x);
                float yy1 = fmaxf(a.y, bb.y);
                float xx2 = fminf(a.z, bb.z);
                float yy2 = fminf(a.w, bb.w);
                float iw = fmaxf(xx2 - xx1, 0.0f);
                float ih = fmaxf(yy2 - yy1, 0.0f);
                float inter = iw * ih;
                float iou = inter / (areaA + areas[col] - inter);
                sup = (iou >= 0.5f);
            }
            uint64_t m = __ballot(sup);
            if (lane == w2) mine = m;
        }
        if (lane < 16) {
            t[(2 * lane + 0) * 1024 + i] = (uint32_t)(mine & 0xFFFFFFFFull);
            t[(2 * lane + 1) * 1024 + i] = (uint32_t)(mine >> 32);
        }
    }
}

// ---------------- Kernel C: group-32 greedy sweep + output ----------------
__global__ __launch_bounds__(64) void sweep_kernel(
    const uint32_t* __restrict__ suppT, const float4* __restrict__ ws_boxes,
    const float* __restrict__ ws_cls, float* __restrict__ out)
{
    const int b    = blockIdx.x;
    const int lane = threadIdx.x;
    const int myw  = lane & 31;
    const uint32_t* base = suppT + (size_t)b * 32 * 1024;

    uint32_t remv = 0, keptw = 0;
    uint4 dgA[8], clA[8], dgB[8], clB[8];

#define LOADG(W, DG, CL) { \
    const uint4* dp_ = (const uint4*)(base + (W) * 1024 + (W) * 32); \
    const uint4* cp_ = (const uint4*)(base + myw * 1024 + (W) * 32); \
    _Pragma("unroll") \
    for (int k_ = 0; k_ < 8; ++k_) { DG[k_] = dp_[k_]; CL[k_] = cp_[k_]; } }

#define STEP(D, C, BBIT) { \
    uint32_t live_ = (((~cur) >> (BBIT)) & 1u) & (uint32_t)((BBIT) < nb); \
    uint32_t msk_ = (uint32_t)0 - live_; \
    kmask |= (live_ << (BBIT)); \
    cur  |= (D) & msk_; \
    acc  |= (C) & msk_; }

#define PROC(W, DG, CL) { \
    const int nb = ((W) == 31) ? (TOPK - 31 * 32) : 32; \
    uint32_t cur = __shfl(remv, (W)); \
    uint32_t kmask = 0, acc = 0; \
    _Pragma("unroll") \
    for (int k_ = 0; k_ < 8; ++k_) { \
        STEP(DG[k_].x, CL[k_].x, 4 * k_ + 0); \
        STEP(DG[k_].y, CL[k_].y, 4 * k_ + 1); \
        STEP(DG[k_].z, CL[k_].z, 4 * k_ + 2); \
        STEP(DG[k_].w, CL[k_].w, 4 * k_ + 3); \
    } \
    remv |= acc; \
    if (myw == (W)) keptw = kmask; }

    LOADG(0, dgA, clA);
    #pragma unroll 1
    for (int w2 = 0; w2 < 16; ++w2) {
        const int wE = 2 * w2, wO = 2 * w2 + 1;
        LOADG(wO, dgB, clB);          // prefetch odd group
        PROC(wE, dgA, clA);
        if (wO + 1 < 32) LOADG(wO + 1, dgA, clA);   // prefetch next even group
        PROC(wO, dgB, clB);
    }

    __shared__ uint32_t skept[32];
    if (lane < 32) skept[lane] = keptw;
    __syncthreads();

    const float4* bx = ws_boxes + (size_t)b * TOPK;
    const float*  bc = ws_cls + (size_t)b * TOPK;
    float4* outr = (float4*)out + (size_t)b * TOPK;
    float*  outc = out + (size_t)BATCH * TOPK * 4 + (size_t)b * TOPK;
    for (int i = lane; i < TOPK; i += 64) {
        uint32_t keep = (skept[i >> 5] >> (i & 31)) & 1u;
        float4 v = bx[i];
        float cv = bc[i];
        outr[i] = keep ? v : make_float4(0.f, 0.f, 0.f, 0.f);
        outc[i] = keep ? cv : 0.0f;
    }
#undef LOADG
#undef STEP
#undef PROC
}

extern "C" void kernel_launch(void* const* d_in, const int* in_sizes, int n_in,
                              void* d_out, int out_size, void* d_ws, size_t ws_size,
                              hipStream_t stream) {
    (void)in_sizes; (void)n_in; (void)out_size; (void)ws_size;
    const float* reg = (const float*)d_in[0];
    const float* cls = (const float*)d_in[1];
    float* out = (float*)d_out;
    char* ws = (char*)d_ws;

    float4*   ws_boxes = (float4*)ws;                      // 16*1000*16 = 256000 B
    float*    ws_cls   = (float*)(ws + 256000);            // 64000 B
    uint32_t* suppT    = (uint32_t*)(ws + 320000);         // 16*32*1024*4 = 2097152 B

    topk_kernel<<<dim3(BATCH), dim3(1024), 0, stream>>>(reg, cls, ws_boxes, ws_cls);
    iou_kernel<<<dim3(16, BATCH), dim3(256), 0, stream>>>(ws_boxes, suppT);
    sweep_kernel<<<dim3(BATCH), dim3(64), 0, stream>>>(suppT, ws_boxes, ws_cls, out);
}